// Round 8
// baseline (339.193 us; speedup 1.0000x reference)
//
#include <hip/hip_runtime.h>

// GCN scatter-aggregate, round 14: fine-sort fused into aggregation (4 dispatches).
//   k_pre  : Wf fragment conversion || zero gcur + deg + dummy h2 row
//   k_part : coarse radix partition (1024 thr, full-line padded writes)
//            + piggybacked global deg atomics
//   k_gemm : h = bf16(rsqrt(deg) * (x @ W))  (MFMA, fp32 accumulate)
//   k_fuse : per bucket: stream pairs region twice -> dst-sorted src list in
//            LDS -> per-wave gather/sum -> out = rsqrt(hist)*sum + bias.
//            No global srcs/rowptr/rend/dis arrays at all.
// Inputs: x fp32 [N,256], edge_index int32 [2,E] (row=dst, col=src),
//         W fp32 [256,128], bias fp32 [128]. Output fp32 [N,128].

#define N_FEAT 256
#define N_HID  128
#define D_BITS 8    // coarse bucket = dst >> 8 (256 dsts/bucket)
#define NBMAX 392   // ceil(100000/256) = 391
#define CAP  6144   // per-bucket capacity (padded mean ~5503, +8 sigma margin)
#define TILE 4096   // edges per k_part block
#define PADTILE 6848  // max padded block total (TILE + NBMAX*7, rounded up)

typedef float fx4    __attribute__((ext_vector_type(4)));
typedef float f32x16 __attribute__((ext_vector_type(16)));
typedef short bf16x8 __attribute__((ext_vector_type(8)));
typedef unsigned int u32x4 __attribute__((ext_vector_type(4)));

__device__ __forceinline__ float bf2f(unsigned int u) {
    return __uint_as_float(u << 16);
}
__device__ __forceinline__ float bf2f_hi(unsigned int u) {
    return __uint_as_float(u & 0xFFFF0000u);
}
__device__ __forceinline__ unsigned int f2bf(float f) {
    unsigned int u = __float_as_uint(f);
    return (u + 0x7FFFu + ((u >> 16) & 1u)) >> 16;  // round-nearest-even
}
__device__ __forceinline__ float deg2dis(int dg) {
    return (dg > 0) ? rsqrtf((float)dg) : 0.0f;
}

// ---- k_pre: Wf fragment conversion + gcur/deg/dummy-row zero ----------------
// Blocks 0..15: W -> fragment-ready bf16 (B-operand of mfma_f32_32x32x16_bf16).
// Frag f = kstep*4 + ntile; lane supplies B[k=kstep*16+(lane>>5)*8+j][n=ntile*32+(lane&31)].
// Block 16: zero gcur + dummy h2 row. All 64 blocks: grid-stride zero deg.
__global__ __launch_bounds__(256) void k_pre(const float* __restrict__ W,
                                             uint4* __restrict__ Wf,
                                             int* __restrict__ gcur,
                                             int* __restrict__ deg,
                                             unsigned int* __restrict__ h2d,
                                             int N) {
    const int b = blockIdx.x, t = threadIdx.x;
    if (b < 16) {
        int i = b * 256 + t;                  // 0..4095
        int lane = i & 63, f = i >> 6;
        int kstep = f >> 2, nt = f & 3;
        int n  = nt * 32 + (lane & 31);
        int kb = kstep * 16 + (lane >> 5) * 8;
        unsigned s[8];
#pragma unroll
        for (int j = 0; j < 8; ++j) s[j] = f2bf(W[(kb + j) * N_HID + n]);
        uint4 o;
        o.x = s[0] | (s[1] << 16);
        o.y = s[2] | (s[3] << 16);
        o.z = s[4] | (s[5] << 16);
        o.w = s[6] | (s[7] << 16);
        Wf[i] = o;
    } else if (b == 16) {
        gcur[t]       = 0;
        gcur[t + 256] = 0;
        if (t < 64) h2d[t] = 0;               // dummy zero row h2[N]
    }
    for (int i = b * 256 + t; i < N; i += 64 * 256) deg[i] = 0;
}

// ---- pass 1: partition edges into coarse buckets, full-line runs ------------
// 1024 threads (16 waves). Per-bucket runs padded to multiples of 8 pairs
// (64B) inside LDS; dummies (src=N, dst=b<<8) fill pad slots so the emit
// loop writes whole lines, coalesced, exactly once. Piggybacks global
// per-node degree atomics (feeds k_gemm's rsqrt scale).
__global__ __launch_bounds__(1024) void k_part(const int* __restrict__ ei,
                                               int* __restrict__ gcur,
                                               int* __restrict__ deg,
                                               uint2* __restrict__ pairs,
                                               int E, int nb, int N) {
    __shared__ int hist[NBMAX], lbase[NBMAX], gbase[NBMAX], cur[NBMAX];
    __shared__ int sc[512];
    __shared__ uint2 sorted[PADTILE];   // 54.8 KB (total LDS ~63.1 KB)
    const int t  = threadIdx.x;
    const int e0 = blockIdx.x * TILE;
    const int cnt = min(TILE, E - e0);

    for (int b = t; b < nb; b += 1024) hist[b] = 0;
    __syncthreads();
    for (int i = t; i < cnt; i += 1024) {
        int d = ei[e0 + i];
        atomicAdd(&hist[d >> D_BITS], 1);
        atomicAdd(&deg[d], 1);              // device-scope, fire-and-forget
    }
    __syncthreads();

    // scan over PADDED counts (512 slots, t<512 active; all-thread barriers)
    int v = 0;
    if (t < 512) {
        int h = (t < nb) ? hist[t] : 0;
        v = (h + 7) & ~7;
        sc[t] = v;
    }
    __syncthreads();
    for (int off = 1; off < 512; off <<= 1) {
        int a = 0;
        if (t < 512) { a = sc[t]; if (t >= off) a += sc[t - off]; }
        __syncthreads();
        if (t < 512) sc[t] = a;
        __syncthreads();
    }
    if (t < nb) lbase[t] = sc[t] - v;
    __syncthreads();
    const int P = sc[511];              // padded block total (<= PADTILE)

    // reserve padded run per bucket; pre-fill pad slots with dummies (LDS)
    for (int b = t; b < nb; b += 1024) {
        int h  = hist[b];
        int hp = (h + 7) & ~7;
        gbase[b] = (hp > 0) ? atomicAdd(&gcur[b], hp) : 0;
        cur[b] = lbase[b];
        uint2 dmy = make_uint2((unsigned)N, (unsigned)(b << D_BITS));
        for (int k = h; k < hp; ++k) sorted[lbase[b] + k] = dmy;
    }
    __syncthreads();

    for (int i = t; i < cnt; i += 1024) {
        int d = ei[e0 + i];
        int s = ei[E + e0 + i];
        int b = d >> D_BITS;
        int p = atomicAdd(&cur[b], 1);
        sorted[p] = make_uint2((unsigned)s, (unsigned)d);
    }
    __syncthreads();

    // emit padded runs: coalesced, every 64B line written exactly once
    for (int i = t; i < P; i += 1024) {
        uint2 pr = sorted[i];
        int b = ((int)pr.y) >> D_BITS;
        pairs[(size_t)b * CAP + gbase[b] + (i - lbase[b])] = pr;
    }
}

// ---- h = bf16(rsqrt(deg) * (x @ W)) via MFMA, no LDS ------------------------
// Block = 4 waves; wave w covers rows mbase+w*32 .. +31, all 128 cols.
__global__ __launch_bounds__(256) void k_gemm(const float* __restrict__ x,
                                              const uint4* __restrict__ Wf,
                                              const int* __restrict__ deg,
                                              unsigned short* __restrict__ h2s,
                                              int N) {
    const int wave = threadIdx.x >> 6;
    const int lane = threadIdx.x & 63;
    const int half = lane >> 5;          // k sub-block 0/1 (8 elems each)
    const int lm   = lane & 31;
    const int mbase = blockIdx.x * 128 + wave * 32;
    const int arow  = min(mbase + lm, N - 1);   // clamp; garbage rows discarded

    const fx4* xr = (const fx4*)(x + (size_t)arow * N_FEAT) + half * 2;

    f32x16 acc0 = {0}, acc1 = {0}, acc2 = {0}, acc3 = {0};

#pragma unroll
    for (int ks = 0; ks < 16; ++ks) {
        fx4 a0 = xr[ks * 4];          // k = ks*16 + half*8 + (0..3)
        fx4 a1 = xr[ks * 4 + 1];      //                  + (4..7)
        union { bf16x8 v; unsigned u[4]; } A;
        A.u[0] = f2bf(a0.x) | (f2bf(a0.y) << 16);
        A.u[1] = f2bf(a0.z) | (f2bf(a0.w) << 16);
        A.u[2] = f2bf(a1.x) | (f2bf(a1.y) << 16);
        A.u[3] = f2bf(a1.z) | (f2bf(a1.w) << 16);
        union { bf16x8 v; uint4 q; } B0, B1, B2, B3;
        B0.q = Wf[(ks * 4 + 0) * 64 + lane];
        B1.q = Wf[(ks * 4 + 1) * 64 + lane];
        B2.q = Wf[(ks * 4 + 2) * 64 + lane];
        B3.q = Wf[(ks * 4 + 3) * 64 + lane];
        acc0 = __builtin_amdgcn_mfma_f32_32x32x16_bf16(A.v, B0.v, acc0, 0, 0, 0);
        acc1 = __builtin_amdgcn_mfma_f32_32x32x16_bf16(A.v, B1.v, acc1, 0, 0, 0);
        acc2 = __builtin_amdgcn_mfma_f32_32x32x16_bf16(A.v, B2.v, acc2, 0, 0, 0);
        acc3 = __builtin_amdgcn_mfma_f32_32x32x16_bf16(A.v, B3.v, acc3, 0, 0, 0);
    }

    // C/D: col = lane&31, row = (r&3) + 8*(r>>2) + 4*(lane>>5)   [m74/m101]
#pragma unroll
    for (int r = 0; r < 16; ++r) {
        int row  = (r & 3) + 8 * (r >> 2) + 4 * half;
        int node = mbase + row;
        if (node < N) {
            float dn = deg2dis(deg[node]);
            size_t o = (size_t)node * N_HID + lm;
            h2s[o +  0] = (unsigned short)f2bf(dn * acc0[r]);
            h2s[o + 32] = (unsigned short)f2bf(dn * acc1[r]);
            h2s[o + 64] = (unsigned short)f2bf(dn * acc2[r]);
            h2s[o + 96] = (unsigned short)f2bf(dn * acc3[r]);
        }
    }
}

// ---- k_fuse: per-bucket fine sort in LDS + aggregation ----------------------
// Block = bucket b (256 dsts). Phase 1: stream pairs region, hist over
// dst&255 (dummies filtered). Phase 2: scan. Phase 3: scatter src ids into
// dst-sorted LDS list. Phase 4: wave w aggregates nodes w*16..w*16+15:
// gather h2 rows via dwordx4 (lane q = dims 8q..+7, group j = edge slot),
// out[n] = rsqrt(hist)*sum + bias. Tail slots clamp to zero row h2[N].
__global__ __launch_bounds__(1024) void k_fuse(const uint2* __restrict__ pairs,
                                               const int* __restrict__ gcur,
                                               const u32x4* __restrict__ h2q,
                                               const float* __restrict__ bias,
                                               float4* __restrict__ out4,
                                               int N) {
    __shared__ int hist[256], cur[256], sc[256];
    __shared__ int lsrc[CAP];          // 24 KB: dst-sorted src ids
    const int t = threadIdx.x;
    const int b = blockIdx.x;
    const int nbk = gcur[b];           // padded count (incl. dummies)
    const uint2* pp = pairs + (size_t)b * CAP;

    if (t < 256) hist[t] = 0;
    __syncthreads();
    for (int i = t; i < nbk; i += 1024) {
        uint2 pr = pp[i];
        if (pr.x != (unsigned)N) atomicAdd(&hist[pr.y & 255], 1);
    }
    __syncthreads();

    int h = 0;
    if (t < 256) { h = hist[t]; sc[t] = h; }
    __syncthreads();
    for (int off = 1; off < 256; off <<= 1) {
        int a = 0;
        if (t < 256) { a = sc[t]; if (t >= off) a += sc[t - off]; }
        __syncthreads();
        if (t < 256) sc[t] = a;
        __syncthreads();
    }
    if (t < 256) cur[t] = sc[t] - h;   // exclusive segment starts
    __syncthreads();

    for (int i = t; i < nbk; i += 1024) {
        uint2 pr = pp[i];
        if (pr.x != (unsigned)N) {
            int p = atomicAdd(&cur[pr.y & 255], 1);
            lsrc[p] = (int)pr.x;
        }
    }
    __syncthreads();

    // ---- aggregation: wave w owns nodes (b<<8)+w*16 .. +15 ----
    const int wave = t >> 6;
    const int lane = t & 63;
    const int j = lane >> 4;      // edge sub-slot within each 4-edge step
    const int q = lane & 15;      // 16B chunk (dims 8q..8q+7) within a row
    const float4* b4 = (const float4*)bias;
    const float4 bv0 = b4[q * 2], bv1 = b4[q * 2 + 1];

    for (int u = 0; u < 16; ++u) {
        const int local = wave * 16 + u;
        const int n = (b << D_BITS) + local;
        if (n >= N) break;                 // uniform across the wave
        const int hh  = hist[local];
        const int end = sc[local];         // inclusive scan = segment end
        float a[8];
#pragma unroll
        for (int k = 0; k < 8; ++k) a[k] = 0.0f;

        for (int i = end - hh; i < end; i += 16) {
#pragma unroll
            for (int g = 0; g < 4; ++g) {
                int idx = i + 4 * g + j;
                int cg  = (idx < end) ? lsrc[idx] : N;  // LDS broadcast read
                u32x4 v = h2q[(size_t)cg * 16 + q];     // dwordx4 gather
                a[0] += bf2f(v[0]);  a[1] += bf2f_hi(v[0]);
                a[2] += bf2f(v[1]);  a[3] += bf2f_hi(v[1]);
                a[4] += bf2f(v[2]);  a[5] += bf2f_hi(v[2]);
                a[6] += bf2f(v[3]);  a[7] += bf2f_hi(v[3]);
            }
        }

        // sum the 4 lane-groups
#pragma unroll
        for (int k = 0; k < 8; ++k) {
            a[k] += __shfl_xor(a[k], 16, 64);
            a[k] += __shfl_xor(a[k], 32, 64);
        }

        if (lane < 16) {
            float dn = (hh > 0) ? rsqrtf((float)hh) : 0.0f;
            float4 o0, o1;
            o0.x = dn * a[0] + bv0.x;  o0.y = dn * a[1] + bv0.y;
            o0.z = dn * a[2] + bv0.z;  o0.w = dn * a[3] + bv0.w;
            o1.x = dn * a[4] + bv1.x;  o1.y = dn * a[5] + bv1.y;
            o1.z = dn * a[6] + bv1.z;  o1.w = dn * a[7] + bv1.w;
            out4[(size_t)n * 32 + q * 2]     = o0;
            out4[(size_t)n * 32 + q * 2 + 1] = o1;
        }
    }
}

extern "C" void kernel_launch(void* const* d_in, const int* in_sizes, int n_in,
                              void* d_out, int out_size, void* d_ws, size_t ws_size,
                              hipStream_t stream) {
    const float* x    = (const float*)d_in[0];   // fp32 [N,256]
    const int*   ei   = (const int*)d_in[1];     // int32 [2,E]
    const float* W    = (const float*)d_in[2];   // fp32 [256,128]
    const float* bias = (const float*)d_in[3];   // fp32 [128]

    const int N = in_sizes[0] / N_FEAT;   // 100000
    const int E = in_sizes[1] / 2;        // 1600000
    const int nb = (N + 255) >> D_BITS;   // 391 coarse buckets

    // workspace layout (~46 MB)
    char* ws = (char*)d_ws;
    size_t off = 0;
    int*          gcur   = (int*)(ws + off);   off += 512 * 4;
    int*          deg    = (int*)(ws + off);   off += (size_t)N * 4;
    uint4*        Wf     = (uint4*)(ws + off); off += 4096 * 16;   // 64 KB
    uint2*        pairs  = (uint2*)(ws + off); off += (size_t)nb * CAP * 8;
    unsigned int* h2     = (unsigned int*)(ws + off);  // (N+1)*64 dwords

    k_pre<<<64, 256, 0, stream>>>(W, (uint4*)Wf, gcur, deg,
                                  h2 + (size_t)N * 64, N);
    k_part<<<(E + TILE - 1) / TILE, 1024, 0, stream>>>(ei, gcur, deg, pairs,
                                                       E, nb, N);
    k_gemm<<<(N + 127) / 128, 256, 0, stream>>>(x, Wf, deg,
                                                (unsigned short*)h2, N);
    k_fuse<<<nb, 1024, 0, stream>>>(pairs, gcur, (const u32x4*)h2, bias,
                                    (float4*)d_out, N);
}